// Round 1
// baseline (497.385 us; speedup 1.0000x reference)
//
#include <hip/hip_runtime.h>
#include <cstdint>

namespace {

constexpr int BPB  = 64;   // batches per block (one wave covers them)
constexpr int NTHR = 128;  // wave0 = bwd chain + LSTM, wave1 = fwd chain
constexpr int RSTR = 37;   // ldsR row stride (4 mats * 9 + 1 pad) -> lane stride 5 mod 32
constexpr int BSTR = 13;   // bounce row stride (12 + 1 pad)

__device__ __forceinline__ float sigm_(float x) {
    return __fdividef(1.0f, 1.0f + __expf(-x));
}
__device__ __forceinline__ float tanh_(float x) {
    return __fdividef(2.0f, 1.0f + __expf(-2.0f * x)) - 1.0f;
}

// Stage CNT consecutive 3x3 matrices for 64 batches into ldsR, coalesced across lanes.
template <int CNT>
__device__ __forceinline__ void stage_R(const float* __restrict__ Rg,
                                        int64_t b0, int t0, int lane,
                                        float* __restrict__ ldsR) {
    constexpr int F = CNT * 9;
    #pragma unroll
    for (int k = 0; k < F; ++k) {
        const int f   = k * BPB + lane;     // flat (seg,off) index, consecutive across lanes
        const int seg = f / F;
        const int off = f - seg * F;
        ldsR[seg * RSTR + off] = Rg[(b0 + seg) * 567 + t0 * 9 + off];
    }
}

// Coalesced store of CNT timesteps (CNT*3 floats) per batch from bounce to out.
template <int CNT>
__device__ __forceinline__ void store_bounce(float* __restrict__ outg,
                                             int64_t b0, int tout0, int lane,
                                             const float* __restrict__ bnc) {
    constexpr int F = CNT * 3;
    #pragma unroll
    for (int k = 0; k < F; ++k) {
        const int f   = k * BPB + lane;
        const int seg = f / F;
        const int off = f - seg * F;
        outg[(b0 + seg) * 192 + tout0 * 3 + off] = bnc[seg * BSTR + off];
    }
}

__global__ __launch_bounds__(NTHR, 2) void gaze_kernel(
    const float* __restrict__ dirg,   // (B,3)
    const float* __restrict__ Rg,     // (B,63,3,3)
    const float* __restrict__ w_ih,   // (12,3)
    const float* __restrict__ w_hh,   // (12,3)
    const float* __restrict__ b_ih,   // (12)
    const float* __restrict__ b_hh,   // (12)
    float* __restrict__ outg)         // (B,64,3)
{
    __shared__ float ldsR[2][BPB * RSTR];
    __shared__ float bnc[2][BPB * BSTR];

    const int tid  = threadIdx.x;
    const int wid  = tid >> 6;
    const int lane = tid & 63;
    const int64_t b0 = (int64_t)blockIdx.x * BPB;
    const int64_t b  = b0 + lane;

    const float dx = dirg[b * 3 + 0];
    const float dy = dirg[b * 3 + 1];
    const float dz = dirg[b * 3 + 2];

    // running prefix matrix (bwd M for wave0, fwd P for wave1), starts identity
    float M[9] = {1.f, 0.f, 0.f, 0.f, 1.f, 0.f, 0.f, 0.f, 1.f};
    float dp[32][3];   // wave0 only: dirs[0..31], kept in registers for the LSTM

    // 8 chunk-phases (4 timesteps each); both waves lockstep so barriers are uniform.
    #pragma unroll
    for (int c = 0; c < 8; ++c) {
        __syncthreads();   // ldsR safe to overwrite (previous chunk fully consumed/stored)
        if (wid == 0) {
            const int t0 = (7 - c) * 4;          // bwd chunks descending: 28,24,...,0
            stage_R<4>(Rg, b0, t0, lane, ldsR[0]);
        } else {
            const int t0 = 32 + c * 4;           // fwd chunks ascending: 32,...,60
            if (c < 7) stage_R<4>(Rg, b0, t0, lane, ldsR[1]);
            else       stage_R<3>(Rg, b0, t0, lane, ldsR[1]);
        }
        __syncthreads();

        if (wid == 0) {
            const int t0 = (7 - c) * 4;
            #pragma unroll
            for (int s = 0; s < 4; ++s) {
                const int tt = 3 - s;            // within chunk: t descending
                const float* Rl = &ldsR[0][lane * RSTR + tt * 9];
                const float r00=Rl[0], r01=Rl[1], r02=Rl[2];
                const float r10=Rl[3], r11=Rl[4], r12=Rl[5];
                const float r20=Rl[6], r21=Rl[7], r22=Rl[8];
                float n0, n1, n2;
                // M <- M @ R^T
                n0 = M[0]*r00 + M[1]*r01 + M[2]*r02;
                n1 = M[0]*r10 + M[1]*r11 + M[2]*r12;
                n2 = M[0]*r20 + M[1]*r21 + M[2]*r22;
                M[0]=n0; M[1]=n1; M[2]=n2;
                n0 = M[3]*r00 + M[4]*r01 + M[5]*r02;
                n1 = M[3]*r10 + M[4]*r11 + M[5]*r12;
                n2 = M[3]*r20 + M[4]*r21 + M[5]*r22;
                M[3]=n0; M[4]=n1; M[5]=n2;
                n0 = M[6]*r00 + M[7]*r01 + M[8]*r02;
                n1 = M[6]*r10 + M[7]*r11 + M[8]*r12;
                n2 = M[6]*r20 + M[7]*r21 + M[8]*r22;
                M[6]=n0; M[7]=n1; M[8]=n2;
                const int t = t0 + tt;
                const float vx = M[0]*dx + M[1]*dy + M[2]*dz;
                const float vy = M[3]*dx + M[4]*dy + M[5]*dz;
                const float vz = M[6]*dx + M[7]*dy + M[8]*dz;
                dp[t][0] = vx; dp[t][1] = vy; dp[t][2] = vz;
                bnc[0][lane * BSTR + tt * 3 + 0] = vx;
                bnc[0][lane * BSTR + tt * 3 + 1] = vy;
                bnc[0][lane * BSTR + tt * 3 + 2] = vz;
            }
        } else {
            const int CNTc = (c < 7) ? 4 : 3;
            #pragma unroll
            for (int tt = 0; tt < 4; ++tt) {
                if (tt < CNTc) {                 // folds: c and tt are compile-time
                    const float* Rl = &ldsR[1][lane * RSTR + tt * 9];
                    const float r00=Rl[0], r01=Rl[1], r02=Rl[2];
                    const float r10=Rl[3], r11=Rl[4], r12=Rl[5];
                    const float r20=Rl[6], r21=Rl[7], r22=Rl[8];
                    float n0, n1, n2;
                    // P <- P @ R
                    n0 = M[0]*r00 + M[1]*r10 + M[2]*r20;
                    n1 = M[0]*r01 + M[1]*r11 + M[2]*r21;
                    n2 = M[0]*r02 + M[1]*r12 + M[2]*r22;
                    M[0]=n0; M[1]=n1; M[2]=n2;
                    n0 = M[3]*r00 + M[4]*r10 + M[5]*r20;
                    n1 = M[3]*r01 + M[4]*r11 + M[5]*r21;
                    n2 = M[3]*r02 + M[4]*r12 + M[5]*r22;
                    M[3]=n0; M[4]=n1; M[5]=n2;
                    n0 = M[6]*r00 + M[7]*r10 + M[8]*r20;
                    n1 = M[6]*r01 + M[7]*r11 + M[8]*r21;
                    n2 = M[6]*r02 + M[7]*r12 + M[8]*r22;
                    M[6]=n0; M[7]=n1; M[8]=n2;
                    bnc[1][lane * BSTR + tt * 3 + 0] = M[0]*dx + M[1]*dy + M[2]*dz;
                    bnc[1][lane * BSTR + tt * 3 + 1] = M[3]*dx + M[4]*dy + M[5]*dz;
                    bnc[1][lane * BSTR + tt * 3 + 2] = M[6]*dx + M[7]*dy + M[8]*dz;
                }
            }
        }
        __syncthreads();   // bounce complete (cross-lane read next)

        if (wid == 0) {
            store_bounce<4>(outg, b0, (7 - c) * 4, lane, bnc[0]);      // out t = mat t
        } else {
            if (c < 7) store_bounce<4>(outg, b0, 33 + c * 4, lane, bnc[1]);  // out t = mat t + 1
            else       store_bounce<3>(outg, b0, 61, lane, bnc[1]);
        }
    }

    // ---- wave0: 33-step LSTM over dirs[0..32]; only hs[32] is needed (center replace)
    if (wid == 0) {
        float wi[12][3], wh[12][3], bsum[12];
        #pragma unroll
        for (int g = 0; g < 12; ++g) {          // uniform loads -> SGPRs
            wi[g][0] = w_ih[g*3+0]; wi[g][1] = w_ih[g*3+1]; wi[g][2] = w_ih[g*3+2];
            wh[g][0] = w_hh[g*3+0]; wh[g][1] = w_hh[g*3+1]; wh[g][2] = w_hh[g*3+2];
            bsum[g]  = b_ih[g] + b_hh[g];
        }
        float h[3]  = {0.f, 0.f, 0.f};
        float cc[3] = {0.f, 0.f, 0.f};
        #pragma unroll
        for (int t = 0; t < 33; ++t) {
            const float x0 = (t < 32) ? dp[t][0] : dx;
            const float x1 = (t < 32) ? dp[t][1] : dy;
            const float x2 = (t < 32) ? dp[t][2] : dz;
            float ga[12];
            #pragma unroll
            for (int g = 0; g < 12; ++g)
                ga[g] = bsum[g] + wi[g][0]*x0 + wi[g][1]*x1 + wi[g][2]*x2
                                + wh[g][0]*h[0] + wh[g][1]*h[1] + wh[g][2]*h[2];
            float ig[3], fg[3], gg[3], og[3];
            #pragma unroll
            for (int j = 0; j < 3; ++j) {
                ig[j] = sigm_(ga[j]);
                fg[j] = sigm_(ga[3 + j]);
                gg[j] = tanh_(ga[6 + j]);
                og[j] = sigm_(ga[9 + j]);
            }
            #pragma unroll
            for (int j = 0; j < 3; ++j) {
                cc[j] = fg[j] * cc[j] + ig[j] * gg[j];
                h[j]  = og[j] * tanh_(cc[j]);
            }
        }
        outg[b * 192 + 96 + 0] = h[0];
        outg[b * 192 + 96 + 1] = h[1];
        outg[b * 192 + 96 + 2] = h[2];
    }
}

}  // namespace

extern "C" void kernel_launch(void* const* d_in, const int* in_sizes, int n_in,
                              void* d_out, int out_size, void* d_ws, size_t ws_size,
                              hipStream_t stream) {
    const float* dirg = (const float*)d_in[0];
    const float* Rg   = (const float*)d_in[1];
    // d_in[2] = S_diag: unused by the reference forward
    const float* wih  = (const float*)d_in[3];
    const float* whh  = (const float*)d_in[4];
    const float* bih  = (const float*)d_in[5];
    const float* bhh  = (const float*)d_in[6];
    float* outg = (float*)d_out;

    const int B = in_sizes[0] / 3;      // 65536
    const int grid = B / BPB;           // 1024 blocks of 128 threads
    gaze_kernel<<<grid, NTHR, 0, stream>>>(dirg, Rg, wih, whh, bih, bhh, outg);
}

// Round 2
// 291.235 us; speedup vs baseline: 1.7078x; 1.7078x over previous
//
#include <hip/hip_runtime.h>
#include <cstdint>

namespace {

constexpr int BPB  = 64;     // batches per block
constexpr int NTHR = 128;    // wave0: bwd chain + LSTM; wave1: fwd chain (fully independent)
constexpr int RSTR = 37;     // LDS row stride in floats (odd -> conflict-free b32 r/w)
constexpr int ROWF = 567;    // floats per R_mode batch row (63*9)
constexpr int OUTF = 192;    // floats per output batch row (64*3)

__device__ __forceinline__ float sigm_(float x) {
    return __fdividef(1.0f, 1.0f + __expf(-x));
}
__device__ __forceinline__ float tanh_(float x) {
    return __fdividef(2.0f, 1.0f + __expf(-2.0f * x)) - 1.0f;
}

// same-wave LDS write->read fence (no __syncthreads: waves never share LDS)
__device__ __forceinline__ void lds_fence() {
    asm volatile("s_waitcnt lgkmcnt(0)" ::: "memory");
    __builtin_amdgcn_sched_barrier(0);
}

// Issue the 9 coalesced float4 loads for one 4-timestep chunk (36 floats x 64 batches).
__device__ __forceinline__ void issue9(const float* __restrict__ Rg, int64_t b0,
                                       int lane, int t0f, bool clamp, int64_t ntot,
                                       float4* nxt) {
    #pragma unroll
    for (int k = 0; k < 9; ++k) {
        const int f4  = k * 64 + lane;          // 576 float4 = 64 segs x 9
        const int seg = f4 / 9;
        const int off = f4 - seg * 9;
        int64_t g = (b0 + seg) * (int64_t)ROWF + t0f + off * 4;
        if (clamp && g > ntot - 4) g = ntot - 4;   // tail chunk: stay inside array
        nxt[k] = *reinterpret_cast<const float4*>(Rg + g);
    }
}

// Scatter the prefetched regs into this wave's LDS buffer (b32, conflict-free).
__device__ __forceinline__ void write9(float* __restrict__ buf, int lane,
                                       const float4* nxt) {
    #pragma unroll
    for (int k = 0; k < 9; ++k) {
        const int f4  = k * 64 + lane;
        const int seg = f4 / 9;
        const int off = f4 - seg * 9;
        float* p = buf + seg * RSTR + off * 4;
        p[0] = nxt[k].x; p[1] = nxt[k].y; p[2] = nxt[k].z; p[3] = nxt[k].w;
    }
}

__global__ __launch_bounds__(NTHR, 2) void gaze_kernel(
    const float* __restrict__ dirg,   // (B,3)
    const float* __restrict__ Rg,     // (B,63,3,3)
    const float* __restrict__ w_ih,   // (12,3)
    const float* __restrict__ w_hh,   // (12,3)
    const float* __restrict__ b_ih,   // (12)
    const float* __restrict__ b_hh,   // (12)
    float* __restrict__ outg,         // (B,64,3)
    int64_t ntot)                     // B*567
{
    __shared__ float ldsR[2][2][BPB * RSTR];   // [wave][dbuf]  37.9 KB total

    const int tid  = threadIdx.x;
    const int wid  = tid >> 6;
    const int lane = tid & 63;
    const int64_t b0 = (int64_t)blockIdx.x * BPB;
    const int64_t b  = b0 + lane;

    const float dx = dirg[b * 3 + 0];
    const float dy = dirg[b * 3 + 1];
    const float dz = dirg[b * 3 + 2];

    float M[9] = {1.f, 0.f, 0.f, 0.f, 1.f, 0.f, 0.f, 0.f, 1.f};

    if (wid == 0) {
        // ---------------- wave0: bwd chain t=31..0, then LSTM, then store t=0..32
        float* const L0 = &ldsR[0][0][0];
        float* const L1 = &ldsR[0][1][0];
        float4 pfA[9], pfB[9];
        issue9(Rg, b0, lane, 7 * 36, false, ntot, pfA);   // chunk0 (t0=28)
        issue9(Rg, b0, lane, 6 * 36, false, ntot, pfB);   // chunk1 (t0=24)
        write9(L0, lane, pfA);

        float dpf[96];   // dirs[t][j] for t=0..31, fully compile-time indexed

        #pragma unroll
        for (int c = 0; c < 8; ++c) {
            if (c + 2 < 8) {   // prefetch chunk c+2 into the reg set freed last iter
                if ((c & 1) == 0) issue9(Rg, b0, lane, (5 - c) * 36, false, ntot, pfA);
                else              issue9(Rg, b0, lane, (5 - c) * 36, false, ntot, pfB);
            }
            if (c + 1 < 8) {   // stage chunk c+1 (compiler emits counted vmcnt)
                if ((c & 1) == 0) write9(L1, lane, pfB);
                else              write9(L0, lane, pfA);
            }
            lds_fence();
            const float* row = (((c & 1) == 0) ? L0 : L1) + lane * RSTR;
            const int t0 = (7 - c) * 4;
            #pragma unroll
            for (int s = 0; s < 4; ++s) {
                const int tt = 3 - s;                    // descending t within chunk
                const float* Rl = row + tt * 9;
                const float r00=Rl[0], r01=Rl[1], r02=Rl[2];
                const float r10=Rl[3], r11=Rl[4], r12=Rl[5];
                const float r20=Rl[6], r21=Rl[7], r22=Rl[8];
                float n0, n1, n2;
                // M <- M @ R^T
                n0 = M[0]*r00 + M[1]*r01 + M[2]*r02;
                n1 = M[0]*r10 + M[1]*r11 + M[2]*r12;
                n2 = M[0]*r20 + M[1]*r21 + M[2]*r22;
                M[0]=n0; M[1]=n1; M[2]=n2;
                n0 = M[3]*r00 + M[4]*r01 + M[5]*r02;
                n1 = M[3]*r10 + M[4]*r11 + M[5]*r12;
                n2 = M[3]*r20 + M[4]*r21 + M[5]*r22;
                M[3]=n0; M[4]=n1; M[5]=n2;
                n0 = M[6]*r00 + M[7]*r01 + M[8]*r02;
                n1 = M[6]*r10 + M[7]*r11 + M[8]*r12;
                n2 = M[6]*r20 + M[7]*r21 + M[8]*r22;
                M[6]=n0; M[7]=n1; M[8]=n2;
                const int t = t0 + tt;
                dpf[t*3+0] = M[0]*dx + M[1]*dy + M[2]*dz;
                dpf[t*3+1] = M[3]*dx + M[4]*dy + M[5]*dz;
                dpf[t*3+2] = M[6]*dx + M[7]*dy + M[8]*dz;
            }
        }

        // LSTM: 33 steps over dirs[0..32]; only hs[32] is consumed
        float wi[12][3], wh[12][3], bsum[12];
        #pragma unroll
        for (int g = 0; g < 12; ++g) {   // uniform -> SGPRs
            wi[g][0] = w_ih[g*3+0]; wi[g][1] = w_ih[g*3+1]; wi[g][2] = w_ih[g*3+2];
            wh[g][0] = w_hh[g*3+0]; wh[g][1] = w_hh[g*3+1]; wh[g][2] = w_hh[g*3+2];
            bsum[g]  = b_ih[g] + b_hh[g];
        }
        float h[3]  = {0.f, 0.f, 0.f};
        float cc[3] = {0.f, 0.f, 0.f};
        #pragma unroll
        for (int t = 0; t < 33; ++t) {
            const float x0 = (t < 32) ? dpf[t*3+0] : dx;
            const float x1 = (t < 32) ? dpf[t*3+1] : dy;
            const float x2 = (t < 32) ? dpf[t*3+2] : dz;
            float ga[12];
            #pragma unroll
            for (int g = 0; g < 12; ++g)
                ga[g] = bsum[g] + wi[g][0]*x0 + wi[g][1]*x1 + wi[g][2]*x2
                                + wh[g][0]*h[0] + wh[g][1]*h[1] + wh[g][2]*h[2];
            float ig[3], fg[3], gg[3], og[3];
            #pragma unroll
            for (int j = 0; j < 3; ++j) {
                ig[j] = sigm_(ga[j]);
                fg[j] = sigm_(ga[3 + j]);
                gg[j] = tanh_(ga[6 + j]);
                og[j] = sigm_(ga[9 + j]);
            }
            #pragma unroll
            for (int j = 0; j < 3; ++j) {
                cc[j] = fg[j] * cc[j] + ig[j] * gg[j];
                h[j]  = og[j] * tanh_(cc[j]);
            }
        }

        // store: row-contiguous per-lane dwordx4 -> full sectors, zero RMW
        float* orow = outg + b * OUTF;
        #pragma unroll
        for (int q = 0; q < 24; ++q) {
            float4 v = make_float4(dpf[4*q+0], dpf[4*q+1], dpf[4*q+2], dpf[4*q+3]);
            *reinterpret_cast<float4*>(orow + 4*q) = v;
        }
        orow[96] = h[0]; orow[97] = h[1]; orow[98] = h[2];

    } else {
        // ---------------- wave1: fwd chain t=32..62 -> out t=33..63
        float* const L0 = &ldsR[1][0][0];
        float* const L1 = &ldsR[1][1][0];
        float4 pfA[9], pfB[9];
        issue9(Rg, b0, lane, 288 +  0, false, ntot, pfA);   // chunk0 (t0=32)
        issue9(Rg, b0, lane, 288 + 36, false, ntot, pfB);   // chunk1 (t0=36)
        write9(L0, lane, pfA);

        float ovf[93];   // out t=33..63

        #pragma unroll
        for (int c = 0; c < 8; ++c) {
            if (c + 2 < 8) {
                const int  t0f = 288 + (c + 2) * 36;
                const bool cl  = (c + 2 == 7);   // last chunk has only 3 mats
                if ((c & 1) == 0) issue9(Rg, b0, lane, t0f, cl, ntot, pfA);
                else              issue9(Rg, b0, lane, t0f, cl, ntot, pfB);
            }
            if (c + 1 < 8) {
                if ((c & 1) == 0) write9(L1, lane, pfB);
                else              write9(L0, lane, pfA);
            }
            lds_fence();
            const float* row = (((c & 1) == 0) ? L0 : L1) + lane * RSTR;
            #pragma unroll
            for (int tt = 0; tt < 4; ++tt) {
                if (tt < ((c < 7) ? 4 : 3)) {           // folds at compile time
                    const float* Rl = row + tt * 9;
                    const float r00=Rl[0], r01=Rl[1], r02=Rl[2];
                    const float r10=Rl[3], r11=Rl[4], r12=Rl[5];
                    const float r20=Rl[6], r21=Rl[7], r22=Rl[8];
                    float n0, n1, n2;
                    // P <- P @ R
                    n0 = M[0]*r00 + M[1]*r10 + M[2]*r20;
                    n1 = M[0]*r01 + M[1]*r11 + M[2]*r21;
                    n2 = M[0]*r02 + M[1]*r12 + M[2]*r22;
                    M[0]=n0; M[1]=n1; M[2]=n2;
                    n0 = M[3]*r00 + M[4]*r10 + M[5]*r20;
                    n1 = M[3]*r01 + M[4]*r11 + M[5]*r21;
                    n2 = M[3]*r02 + M[4]*r12 + M[5]*r22;
                    M[3]=n0; M[4]=n1; M[5]=n2;
                    n0 = M[6]*r00 + M[7]*r10 + M[8]*r20;
                    n1 = M[6]*r01 + M[7]*r11 + M[8]*r21;
                    n2 = M[6]*r02 + M[7]*r12 + M[8]*r22;
                    M[6]=n0; M[7]=n1; M[8]=n2;
                    const int oi = c * 4 + tt;          // 0..30  (out t = 33+oi)
                    ovf[oi*3+0] = M[0]*dx + M[1]*dy + M[2]*dz;
                    ovf[oi*3+1] = M[3]*dx + M[4]*dy + M[5]*dz;
                    ovf[oi*3+2] = M[6]*dx + M[7]*dy + M[8]*dz;
                }
            }
        }

        // store floats 99..191 of the row: 1 b32 + 23 aligned b128
        float* orow = outg + b * OUTF;
        orow[99] = ovf[0];
        #pragma unroll
        for (int q = 0; q < 23; ++q) {
            float4 v = make_float4(ovf[1+4*q], ovf[2+4*q], ovf[3+4*q], ovf[4+4*q]);
            *reinterpret_cast<float4*>(orow + 100 + 4*q) = v;
        }
    }
}

}  // namespace

extern "C" void kernel_launch(void* const* d_in, const int* in_sizes, int n_in,
                              void* d_out, int out_size, void* d_ws, size_t ws_size,
                              hipStream_t stream) {
    const float* dirg = (const float*)d_in[0];
    const float* Rg   = (const float*)d_in[1];
    // d_in[2] = S_diag: unused by the reference forward
    const float* wih  = (const float*)d_in[3];
    const float* whh  = (const float*)d_in[4];
    const float* bih  = (const float*)d_in[5];
    const float* bhh  = (const float*)d_in[6];
    float* outg = (float*)d_out;

    const int B = in_sizes[0] / 3;              // 65536
    const int64_t ntot = (int64_t)in_sizes[1];  // B*567
    const int grid = B / BPB;                   // 1024 blocks x 128 thr
    gaze_kernel<<<grid, NTHR, 0, stream>>>(dirg, Rg, wih, whh, bih, bhh, outg, ntot);
}